// Round 2
// baseline (780.292 us; speedup 1.0000x reference)
//
#include <hip/hip_runtime.h>
#include <math.h>

#define ROWS 16384
#define DD 4096
#define EE 64
#define EPSF 1e-10f

// ---------------------------------------------------------------------------
// Router GEMM [ROWS,4096] x [4096,64] + fused softmax-load accumulation.
// Grid 256 x 512 thr (8 waves). Block tile: 64 rows x 64 experts, k-tile 128.
// lane = row; wave wv owns experts [8*wv, 8*wv+8) -> w reads are wave-uniform
// (e0 via readfirstlane) => s_load_dwordx8, consumed as SGPR operands by FMA.
// h staged in LDS as float4 quads (k4, row) with XOR swizzle: conflict-free
// b128 on both store and load. Register double-buffer on global loads.
// ---------------------------------------------------------------------------
__global__ __launch_bounds__(512) void k_gemm_load(
    const float* __restrict__ h, const float* __restrict__ wr,
    float* __restrict__ logits, float* __restrict__ g_load) {
  __shared__ float4 h4s[32 * 64];     // 32 KB: chunk = k4*64 + (row ^ (k4&15))
  __shared__ float lds_acc[64][65];   // 16.25 KB, padded

  const int t = threadIdx.x;
  const int lane = t & 63;
  const int wv = t >> 6;
  const int e0 = __builtin_amdgcn_readfirstlane(wv * 8);  // uniform expert base
  const int row0 = blockIdx.x * 64;

  float acc[8] = {0.f, 0.f, 0.f, 0.f, 0.f, 0.f, 0.f, 0.f};

  // prefetch k-tile 0 into registers
  float4 pf[4];
#pragma unroll
  for (int i = 0; i < 4; ++i) {
    int f = t + 512 * i;
    int r = f >> 5, kq = f & 31;
    pf[i] = *(const float4*)&h[(size_t)(row0 + r) * DD + 4 * kq];
  }

  for (int k0 = 0; k0 < DD; k0 += 128) {
    __syncthreads();  // previous tile's readers done
    // commit prefetched tile to LDS (swizzled, conflict-free b128 writes)
#pragma unroll
    for (int i = 0; i < 4; ++i) {
      int f = t + 512 * i;
      int r = f >> 5, kq = f & 31;
      h4s[kq * 64 + (r ^ (kq & 15))] = pf[i];
    }
    // issue next tile's global loads (latency hidden behind compute)
    if (k0 + 128 < DD) {
#pragma unroll
      for (int i = 0; i < 4; ++i) {
        int f = t + 512 * i;
        int r = f >> 5, kq = f & 31;
        pf[i] = *(const float4*)&h[(size_t)(row0 + r) * DD + k0 + 128 + 4 * kq];
      }
    }
    __syncthreads();

    const float* wb = wr + (size_t)k0 * EE + e0;  // scalar base
#pragma unroll 4
    for (int kk = 0; kk < 32; ++kk) {
      float4 hv = h4s[kk * 64 + (lane ^ (kk & 15))];
      const float* w4 = wb + kk * 4 * EE;
#pragma unroll
      for (int e = 0; e < 8; ++e) acc[e] = fmaf(hv.x, w4[e], acc[e]);
#pragma unroll
      for (int e = 0; e < 8; ++e) acc[e] = fmaf(hv.y, w4[EE + e], acc[e]);
#pragma unroll
      for (int e = 0; e < 8; ++e) acc[e] = fmaf(hv.z, w4[2 * EE + e], acc[e]);
#pragma unroll
      for (int e = 0; e < 8; ++e) acc[e] = fmaf(hv.w, w4[3 * EE + e], acc[e]);
    }
  }

  // ---- epilogue: logits store + per-row softmax + expert-load accumulation
#pragma unroll
  for (int e = 0; e < 8; ++e) lds_acc[lane][e0 + e] = acc[e];  // 2-way, free
  __syncthreads();

  const int rrow = t >> 3, sub = t & 7;  // 8 threads per row
  float v[8];
#pragma unroll
  for (int j = 0; j < 8; ++j) v[j] = lds_acc[rrow][sub * 8 + j];

  // coalesced-ish raw-logit store (2 x float4 per thread, row-major)
  {
    size_t base = (size_t)(row0 + rrow) * EE + sub * 8;
    *(float4*)&logits[base] = make_float4(v[0], v[1], v[2], v[3]);
    *(float4*)&logits[base + 4] = make_float4(v[4], v[5], v[6], v[7]);
  }

  float m = v[0];
#pragma unroll
  for (int j = 1; j < 8; ++j) m = fmaxf(m, v[j]);
#pragma unroll
  for (int off = 1; off < 8; off <<= 1) m = fmaxf(m, __shfl_xor(m, off, 64));
  float s = 0.f;
  float p[8];
#pragma unroll
  for (int j = 0; j < 8; ++j) { p[j] = __expf(v[j] - m); s += p[j]; }
#pragma unroll
  for (int off = 1; off < 8; off <<= 1) s += __shfl_xor(s, off, 64);
  float inv = 1.f / s;
#pragma unroll
  for (int j = 0; j < 8; ++j) lds_acc[rrow][sub * 8 + j] = p[j] * inv;
  __syncthreads();

  if (t < 64) {  // one wave: column-sum of probs -> one atomic per expert
    float ls = 0.f;
#pragma unroll 8
    for (int r = 0; r < 64; ++r) ls += lds_acc[r][t];
    atomicAdd(&g_load[t], ls);
  }
}

// ---------------------------------------------------------------------------
// penalty -> log(load/mean + eps). 1 block x 64 threads.
// ---------------------------------------------------------------------------
__global__ void k_penalty(const float* __restrict__ g_load,
                          float* __restrict__ g_lp) {
  int t = threadIdx.x;
  float v = g_load[t];
  float s = v;
#pragma unroll
  for (int off = 32; off > 0; off >>= 1) s += __shfl_xor(s, off, 64);
  float mean = s * (1.f / 64.f);
  float pen = v / (mean + EPSF);
  g_lp[t] = logf(pen + EPSF);
}

// ---------------------------------------------------------------------------
// adjusted logits (in place) + top-2 indices (written as floats).
// ---------------------------------------------------------------------------
__global__ __launch_bounds__(256) void k_top2(float* __restrict__ logits,
                                              const float* __restrict__ g_lp,
                                              float* __restrict__ idx_out) {
  int t = threadIdx.x;
  int lane = t & 63;
  int wv = t >> 6;
  int row = blockIdx.x * 4 + wv;
  size_t base = (size_t)row * EE;

  float a = logits[base + lane] - g_lp[lane];
  logits[base + lane] = a;

  float v = a;
  int idx = lane;
#pragma unroll
  for (int off = 32; off > 0; off >>= 1) {
    float ov = __shfl_xor(v, off, 64);
    int oi = __shfl_xor(idx, off, 64);
    if (ov > v || (ov == v && oi < idx)) { v = ov; idx = oi; }
  }
  int i1 = idx;

  float a2 = (lane == i1) ? -INFINITY : a;
  v = a2;
  idx = lane;
#pragma unroll
  for (int off = 32; off > 0; off >>= 1) {
    float ov = __shfl_xor(v, off, 64);
    int oi = __shfl_xor(idx, off, 64);
    if (ov > v || (ov == v && oi < idx)) { v = ov; idx = oi; }
  }
  int i2 = idx;

  if (lane == 0) {
    idx_out[(size_t)row * 2 + 0] = (float)i1;
    idx_out[(size_t)row * 2 + 1] = (float)i2;
  }
}

// ---------------------------------------------------------------------------
extern "C" void kernel_launch(void* const* d_in, const int* in_sizes, int n_in,
                              void* d_out, int out_size, void* d_ws,
                              size_t ws_size, hipStream_t stream) {
  const float* h = (const float*)d_in[0];   // [4,4096,4096]
  const float* wr = (const float*)d_in[1];  // [4096,64]
  float* out = (float*)d_out;
  float* logits = out;                         // ROWS*EE
  float* idx_out = out + (size_t)ROWS * EE;    // ROWS*2
  float* g_load = (float*)d_ws;                // 64
  float* g_lp = g_load + 64;                   // 64

  hipMemsetAsync(d_ws, 0, 64 * sizeof(float), stream);
  k_gemm_load<<<ROWS / 64, 512, 0, stream>>>(h, wr, logits, g_load);
  k_penalty<<<1, 64, 0, stream>>>(g_load, g_lp);
  k_top2<<<ROWS / 4, 256, 0, stream>>>(logits, g_lp, idx_out);
}

// Round 4
// 423.385 us; speedup vs baseline: 1.8430x; 1.8430x over previous
//
#include <hip/hip_runtime.h>
#include <math.h>

#define ROWS 16384
#define DD   4096
#define EE   64
#define EPSF 1e-10f

#define BM     128               // rows per block
#define KT     32                // k per LDS tile
#define KSPLIT 4
#define KRANGE (DD / KSPLIT)     // 1024
#define NKT    (KRANGE / KT)     // 32
#define HPAD   36                // h LDS row stride (words)

typedef __attribute__((ext_vector_type(8))) short short8;  // 8 bf16
typedef __attribute__((ext_vector_type(4))) float f32x4;   // MFMA C/D

__device__ __forceinline__ short rne_bf16(float f) {
  unsigned u = __float_as_uint(f);
  return (short)((u + 0x7fffu + ((u >> 16) & 1u)) >> 16);
}
__device__ __forceinline__ float bf2f(short s) {
  return __uint_as_float(((unsigned)(unsigned short)s) << 16);
}
// 3-way bf16 split: f ~= p0+p1+p2 to ~2^-26 relative
__device__ __forceinline__ void split3(float f, short& s0, short& s1,
                                       short& s2) {
  s0 = rne_bf16(f);
  float r1 = f - bf2f(s0);
  s1 = rne_bf16(r1);
  s2 = rne_bf16(r1 - bf2f(s1));
}

// ---------------------------------------------------------------------------
// Router GEMM via 3-way-split bf16 MFMA (6 terms ~ full fp32 precision).
// Block 256 thr (4 waves): 128 rows x 64 experts x 1024 k; KSPLIT=4 via
// fp32 atomicAdd partials. Wave: 32 rows = 2 m-tiles x 4 e-tiles (16x16x32).
// ---------------------------------------------------------------------------
__global__ __launch_bounds__(256) void k_gemm(
    const float* __restrict__ h, const float* __restrict__ wr,
    float* __restrict__ logits) {
  __shared__ alignas(16) float hs[2][BM * HPAD];       // 36 KB fp32 h tiles
  __shared__ alignas(16) short wsf[2][3][4][64][8];    // 24 KB frag-ready w

  const int t = threadIdx.x;
  const int lane = t & 63;
  const int wv = t >> 6;
  const int row0 = (blockIdx.x >> 2) * BM;
  const int kb0 = (blockIdx.x & 3) * KRANGE;

  f32x4 acc[2][4] = {};

  const int hr = t >> 3;         // staging row 0..31 (+32*i)
  const int hk = (t & 7) * 4;    // staging k-quad
  const int we = lane;           // w stage: expert column
  const int wq = wv;             // w stage: k-octet

  float4 hpf[4];
  float wpf[8];

  // prefetch tile 0
  {
    const float* hp = h + (size_t)(row0 + hr) * DD + kb0 + hk;
#pragma unroll
    for (int i = 0; i < 4; ++i)
      hpf[i] = *(const float4*)(hp + (size_t)32 * i * DD);
    const float* wp = wr + (size_t)(kb0 + wq * 8) * EE + we;
#pragma unroll
    for (int j = 0; j < 8; ++j) wpf[j] = wp[(size_t)j * EE];
  }

  for (int kt = 0; kt < NKT; ++kt) {
    const int buf = kt & 1;
    __syncthreads();
    // commit h tile (fp32)
#pragma unroll
    for (int i = 0; i < 4; ++i)
      *(float4*)&hs[buf][(hr + 32 * i) * HPAD + hk] = hpf[i];
    // 3-way split + commit w tile in exact B-fragment layout
    {
      short8 p0, p1, p2;
#pragma unroll
      for (int j = 0; j < 8; ++j) {
        short a, b, c;
        split3(wpf[j], a, b, c);
        p0[j] = a; p1[j] = b; p2[j] = c;
      }
      const int lp = wq * 16 + (we & 15);
      const int et = we >> 4;
      *(short8*)&wsf[buf][0][et][lp][0] = p0;
      *(short8*)&wsf[buf][1][et][lp][0] = p1;
      *(short8*)&wsf[buf][2][et][lp][0] = p2;
    }
    // prefetch next tile
    if (kt + 1 < NKT) {
      const int kb = kb0 + (kt + 1) * KT;
      const float* hp = h + (size_t)(row0 + hr) * DD + kb + hk;
#pragma unroll
      for (int i = 0; i < 4; ++i)
        hpf[i] = *(const float4*)(hp + (size_t)32 * i * DD);
      const float* wp = wr + (size_t)(kb + wq * 8) * EE + we;
#pragma unroll
      for (int j = 0; j < 8; ++j) wpf[j] = wp[(size_t)j * EE];
    }
    __syncthreads();

    // B fragments: 3 split-parts x 4 e-tiles (ds_read_b128 each)
    short8 bf[3][4];
#pragma unroll
    for (int p = 0; p < 3; ++p)
#pragma unroll
      for (int et = 0; et < 4; ++et)
        bf[p][et] = *(const short8*)&wsf[buf][p][et][lane][0];

#pragma unroll
    for (int mt = 0; mt < 2; ++mt) {
      const int rl = wv * 32 + mt * 16 + (lane & 15);
      const float* ap = &hs[buf][rl * HPAD + (lane >> 4) * 8];
      float4 a0 = *(const float4*)ap;
      float4 a1 = *(const float4*)(ap + 4);
      float af[8] = {a0.x, a0.y, a0.z, a0.w, a1.x, a1.y, a1.z, a1.w};
      short8 ah0, ah1, ah2;
#pragma unroll
      for (int j = 0; j < 8; ++j) {
        short a, b, c;
        split3(af[j], a, b, c);
        ah0[j] = a; ah1[j] = b; ah2[j] = c;
      }
#pragma unroll
      for (int et = 0; et < 4; ++et) {
        f32x4 c = acc[mt][et];
        c = __builtin_amdgcn_mfma_f32_16x16x32_bf16(ah0, bf[0][et], c, 0, 0, 0);
        c = __builtin_amdgcn_mfma_f32_16x16x32_bf16(ah0, bf[1][et], c, 0, 0, 0);
        c = __builtin_amdgcn_mfma_f32_16x16x32_bf16(ah1, bf[0][et], c, 0, 0, 0);
        c = __builtin_amdgcn_mfma_f32_16x16x32_bf16(ah0, bf[2][et], c, 0, 0, 0);
        c = __builtin_amdgcn_mfma_f32_16x16x32_bf16(ah1, bf[1][et], c, 0, 0, 0);
        c = __builtin_amdgcn_mfma_f32_16x16x32_bf16(ah2, bf[0][et], c, 0, 0, 0);
        acc[mt][et] = c;
      }
    }
  }

  // epilogue: K-split partial accumulate (C layout: col=lane&15, row=quad*4+r)
#pragma unroll
  for (int mt = 0; mt < 2; ++mt) {
    const int rbase = row0 + wv * 32 + mt * 16 + (lane >> 4) * 4;
    const int col = lane & 15;
#pragma unroll
    for (int et = 0; et < 4; ++et) {
#pragma unroll
      for (int r = 0; r < 4; ++r)
        atomicAdd(&logits[(size_t)(rbase + r) * EE + et * 16 + col],
                  acc[mt][et][r]);
    }
  }
}

// ---------------------------------------------------------------------------
// softmax + expert-load accumulation. Block 256 = 4 waves; wave = 32 rows,
// lane = expert. Per-lane register accumulation -> 64 atomics per block.
// ---------------------------------------------------------------------------
__global__ __launch_bounds__(256) void k_softload(
    const float* __restrict__ logits, float* __restrict__ g_load) {
  __shared__ float red[4][64];
  const int lane = threadIdx.x & 63;
  const int wv = threadIdx.x >> 6;
  float accp = 0.f;
#pragma unroll 4
  for (int i = 0; i < 32; ++i) {
    int row = blockIdx.x * 128 + wv * 32 + i;
    float x = logits[(size_t)row * EE + lane];
    float m = x;
#pragma unroll
    for (int off = 32; off > 0; off >>= 1) m = fmaxf(m, __shfl_xor(m, off, 64));
    float p = __expf(x - m);
    float s = p;
#pragma unroll
    for (int off = 32; off > 0; off >>= 1) s += __shfl_xor(s, off, 64);
    accp += p / s;
  }
  red[wv][lane] = accp;
  __syncthreads();
  if (wv == 0) {
    float s = red[0][lane] + red[1][lane] + red[2][lane] + red[3][lane];
    atomicAdd(&g_load[lane], s);
  }
}

// ---------------------------------------------------------------------------
__global__ void k_penalty(const float* __restrict__ g_load,
                          float* __restrict__ g_lp) {
  int t = threadIdx.x;
  float v = g_load[t];
  float s = v;
#pragma unroll
  for (int off = 32; off > 0; off >>= 1) s += __shfl_xor(s, off, 64);
  float mean = s * (1.f / 64.f);
  g_lp[t] = logf(v / (mean + EPSF) + EPSF);
}

// ---------------------------------------------------------------------------
__global__ __launch_bounds__(256) void k_top2(float* __restrict__ logits,
                                              const float* __restrict__ g_lp,
                                              float* __restrict__ idx_out) {
  int t = threadIdx.x;
  int lane = t & 63;
  int wv = t >> 6;
  int row = blockIdx.x * 4 + wv;
  size_t base = (size_t)row * EE;

  float a = logits[base + lane] - g_lp[lane];
  logits[base + lane] = a;

  float v = a;
  int idx = lane;
#pragma unroll
  for (int off = 32; off > 0; off >>= 1) {
    float ov = __shfl_xor(v, off, 64);
    int oi = __shfl_xor(idx, off, 64);
    if (ov > v || (ov == v && oi < idx)) { v = ov; idx = oi; }
  }
  int i1 = idx;

  float a2 = (lane == i1) ? -INFINITY : a;
  v = a2;
  idx = lane;
#pragma unroll
  for (int off = 32; off > 0; off >>= 1) {
    float ov = __shfl_xor(v, off, 64);
    int oi = __shfl_xor(idx, off, 64);
    if (ov > v || (ov == v && oi < idx)) { v = ov; idx = oi; }
  }
  int i2 = idx;

  if (lane == 0) {
    idx_out[(size_t)row * 2 + 0] = (float)i1;
    idx_out[(size_t)row * 2 + 1] = (float)i2;
  }
}

// ---------------------------------------------------------------------------
extern "C" void kernel_launch(void* const* d_in, const int* in_sizes, int n_in,
                              void* d_out, int out_size, void* d_ws,
                              size_t ws_size, hipStream_t stream) {
  const float* h = (const float*)d_in[0];   // [4,4096,4096]
  const float* wr = (const float*)d_in[1];  // [4096,64]
  float* out = (float*)d_out;
  float* logits = out;                         // ROWS*EE
  float* idx_out = out + (size_t)ROWS * EE;    // ROWS*2
  float* g_load = (float*)d_ws;                // 64
  float* g_lp = g_load + 64;                   // 64

  hipMemsetAsync(d_out, 0, (size_t)ROWS * EE * sizeof(float), stream);
  hipMemsetAsync(d_ws, 0, 128 * sizeof(float), stream);
  k_gemm<<<(ROWS / BM) * KSPLIT, 256, 0, stream>>>(h, wr, logits);
  k_softload<<<ROWS / 128, 256, 0, stream>>>(logits, g_load);
  k_penalty<<<1, 64, 0, stream>>>(g_load, g_lp);
  k_top2<<<ROWS / 4, 256, 0, stream>>>(logits, g_lp, idx_out);
}